// Round 1
// baseline (550.123 us; speedup 1.0000x reference)
//
#include <hip/hip_runtime.h>

// ---------- types & helpers ----------
typedef __attribute__((ext_vector_type(8))) short short8;   // 8 bf16 (4 VGPRs)
typedef __attribute__((ext_vector_type(4))) float f32x4;

#define AS1 __attribute__((address_space(1)))
#define AS3 __attribute__((address_space(3)))

__device__ __forceinline__ void gload16(const void* g, void* l) {
  __builtin_amdgcn_global_load_lds((const AS1 unsigned int*)g,
                                   (AS3 unsigned int*)l, 16, 0, 0);
}

__device__ __forceinline__ unsigned short f2bf(float x) {
  unsigned u = __float_as_uint(x);
  u = (u + 0x7FFFu + ((u >> 16) & 1u)) >> 16;  // RNE
  return (unsigned short)u;
}

__device__ __forceinline__ short8 lds8(const unsigned short* p) {
  return *(const short8*)p;
}

// Problem constants
// L=S=2048, N=4, E=1024, H=16, D=64; rows = L*N = 8192
#define LL 2048
#define NB 4
#define EE 1024
#define HH 16
#define DD 64
#define MROWS 8192

// ---------- fp32 -> bf16 convert (grid = n/1024 blocks, 256 thr, 4 elems/thr) ----------
__global__ __launch_bounds__(256) void conv_bf16(const float* __restrict__ src,
                                                 unsigned short* __restrict__ dst) {
  int i = blockIdx.x * 256 + threadIdx.x;
  float4 v = ((const float4*)src)[i];
  ushort4 o;
  o.x = f2bf(v.x); o.y = f2bf(v.y); o.z = f2bf(v.z); o.w = f2bf(v.w);
  ((ushort4*)dst)[i] = o;
}

// ---------- GEMM: C[M=8192, N=1024] = A[8192,1024] * B[1024,1024]^T + bias ----------
// A,B bf16 row-major over K. MODE 0: write bf16 head layout [n,h,l,d]
// MODE 1: write bf16 transposed head layout [n,h,d,s]
// MODE 2: write fp32 row-major to outf
template <int MODE>
__global__ __launch_bounds__(256) void gemm_bt(const unsigned short* __restrict__ A,
                                               const unsigned short* __restrict__ B,
                                               const float* __restrict__ bias,
                                               unsigned short* __restrict__ outb,
                                               float* __restrict__ outf) {
  constexpr int K = 1024;
  __shared__ __align__(16) unsigned short As[128 * 32];
  __shared__ __align__(16) unsigned short Bs[128 * 32];
  const int tid = threadIdx.x;
  const int lane = tid & 63, w = tid >> 6;
  const int wr = w >> 1, wc = w & 1;           // 2x2 waves, each 64x64
  const int lrow = lane & 15, lg = lane >> 4;
  const int m0 = blockIdx.y * 128, n0 = blockIdx.x * 128;

  f32x4 acc[4][4] = {};

  const int srow = tid >> 2, sseg = tid & 3;   // staging map: 64 rows x 4 16B-segs
  for (int k0 = 0; k0 < K; k0 += 32) {
    __syncthreads();
    const unsigned short* ga = A + (size_t)(m0 + srow) * K + k0 + sseg * 8;
    gload16(ga,            (char*)As + tid * 16);
    gload16(ga + 64 * K,   (char*)As + tid * 16 + 4096);
    const unsigned short* gb = B + (size_t)(n0 + srow) * K + k0 + sseg * 8;
    gload16(gb,            (char*)Bs + tid * 16);
    gload16(gb + 64 * K,   (char*)Bs + tid * 16 + 4096);
    __syncthreads();

    short8 af[4], bf[4];
#pragma unroll
    for (int mt = 0; mt < 4; ++mt)
      af[mt] = lds8(As + (wr * 64 + mt * 16 + lrow) * 32 + lg * 8);
#pragma unroll
    for (int nt = 0; nt < 4; ++nt)
      bf[nt] = lds8(Bs + (wc * 64 + nt * 16 + lrow) * 32 + lg * 8);
#pragma unroll
    for (int mt = 0; mt < 4; ++mt)
#pragma unroll
      for (int nt = 0; nt < 4; ++nt)
        acc[mt][nt] = __builtin_amdgcn_mfma_f32_16x16x32_bf16(af[mt], bf[nt],
                                                              acc[mt][nt], 0, 0, 0);
  }

#pragma unroll
  for (int mt = 0; mt < 4; ++mt) {
#pragma unroll
    for (int nt = 0; nt < 4; ++nt) {
      const int col = n0 + wc * 64 + nt * 16 + lrow;
      const float bv = bias[col];
#pragma unroll
      for (int r = 0; r < 4; ++r) {
        const int row = m0 + wr * 64 + mt * 16 + lg * 4 + r;  // token-row = l*4+n
        const float v = acc[mt][nt][r] + bv;
        if (MODE == 0) {
          const int l = row >> 2, n = row & 3, h = col >> 6, d = col & 63;
          outb[(((size_t)(n * HH + h)) * LL + l) * DD + d] = f2bf(v);
        } else if (MODE == 1) {
          const int s = row >> 2, n = row & 3, h = col >> 6, d = col & 63;
          outb[(((size_t)(n * HH + h)) * DD + d) * LL + s] = f2bf(v);
        } else {
          outf[(size_t)row * EE + col] = v;
        }
      }
    }
  }
}

// ---------- flash attention per (n,h): 64 q-rows per block ----------
// qh,kh: [nh][seq][64] bf16 ; vth: [nh][64][2048] bf16 (transposed)
// oh: [8192][1024] bf16 ; mbuf,zbuf: [nh][2048] fp32
__global__ __launch_bounds__(256) void flash_attn(const unsigned short* __restrict__ qh,
                                                  const unsigned short* __restrict__ kh,
                                                  const unsigned short* __restrict__ vth,
                                                  unsigned short* __restrict__ oh,
                                                  float* __restrict__ mbuf,
                                                  float* __restrict__ zbuf) {
  __shared__ __align__(16) unsigned short Qs[64 * 64];
  __shared__ __align__(16) unsigned short Ks[64 * 64];
  __shared__ __align__(16) unsigned short Vts[64 * 64];
  __shared__ __align__(16) unsigned short Ps[64 * 64];
  const int tid = threadIdx.x, lane = tid & 63, w = tid >> 6;
  const int lrow = lane & 15, lg = lane >> 4;
  const int nh = blockIdx.y;
  const int l0 = blockIdx.x * 64;

  const unsigned short* qbase = qh + ((size_t)nh * LL + l0) * DD;  // contiguous 8KB
  const unsigned short* kbase = kh + (size_t)nh * LL * DD;
  const unsigned short* vbase = vth + (size_t)nh * DD * LL;

  gload16(qbase + tid * 8,        (char*)Qs + tid * 16);
  gload16(qbase + tid * 8 + 2048, (char*)Qs + tid * 16 + 4096);
  __syncthreads();
  short8 qa0 = lds8(Qs + (w * 16 + lrow) * 64 + lg * 8);
  short8 qa1 = lds8(Qs + (w * 16 + lrow) * 64 + lg * 8 + 32);

  float mrow[4], zrow[4];
  f32x4 acco[4] = {};
#pragma unroll
  for (int r = 0; r < 4; ++r) { mrow[r] = -1e30f; zrow[r] = 0.f; }

  const int vd = tid >> 3, vseg = tid & 7;     // Vt staging: 32 rows x 8 segs
  for (int s0 = 0; s0 < LL; s0 += 64) {
    __syncthreads();
    gload16(kbase + (size_t)s0 * DD + tid * 8,        (char*)Ks + tid * 16);
    gload16(kbase + (size_t)s0 * DD + tid * 8 + 2048, (char*)Ks + tid * 16 + 4096);
    gload16(vbase + (size_t)vd * LL + s0 + vseg * 8,        (char*)Vts + tid * 16);
    gload16(vbase + (size_t)(vd + 32) * LL + s0 + vseg * 8, (char*)Vts + tid * 16 + 4096);
    __syncthreads();

    f32x4 sc[4];
#pragma unroll
    for (int ct = 0; ct < 4; ++ct) {
      short8 b0 = lds8(Ks + (ct * 16 + lrow) * 64 + lg * 8);
      short8 b1 = lds8(Ks + (ct * 16 + lrow) * 64 + lg * 8 + 32);
      f32x4 a = {};
      a = __builtin_amdgcn_mfma_f32_16x16x32_bf16(qa0, b0, a, 0, 0, 0);
      a = __builtin_amdgcn_mfma_f32_16x16x32_bf16(qa1, b1, a, 0, 0, 0);
      sc[ct] = a;
    }

    float p[4][4];
#pragma unroll
    for (int r = 0; r < 4; ++r) {
      float t = fmaxf(fmaxf(sc[0][r], sc[1][r]), fmaxf(sc[2][r], sc[3][r]));
      t = fmaxf(t, __shfl_xor(t, 1));
      t = fmaxf(t, __shfl_xor(t, 2));
      t = fmaxf(t, __shfl_xor(t, 4));
      t = fmaxf(t, __shfl_xor(t, 8));
      t *= 0.125f;                               // exact pow-2 scale
      const float mnew = fmaxf(mrow[r], t);
      const float f = __expf(mrow[r] - mnew);
      mrow[r] = mnew;
      zrow[r] *= f;
#pragma unroll
      for (int dt = 0; dt < 4; ++dt) acco[dt][r] *= f;
      float ps = 0.f;
#pragma unroll
      for (int ct = 0; ct < 4; ++ct) {
        const float e = __expf(sc[ct][r] * 0.125f - mnew);
        p[ct][r] = e;
        ps += e;
      }
      ps += __shfl_xor(ps, 1);
      ps += __shfl_xor(ps, 2);
      ps += __shfl_xor(ps, 4);
      ps += __shfl_xor(ps, 8);
      zrow[r] += ps;
    }
#pragma unroll
    for (int ct = 0; ct < 4; ++ct)
#pragma unroll
      for (int r = 0; r < 4; ++r)
        Ps[(w * 16 + lg * 4 + r) * 64 + ct * 16 + lrow] = f2bf(p[ct][r]);
    __syncthreads();

    short8 pa0 = lds8(Ps + (w * 16 + lrow) * 64 + lg * 8);
    short8 pa1 = lds8(Ps + (w * 16 + lrow) * 64 + lg * 8 + 32);
#pragma unroll
    for (int dt = 0; dt < 4; ++dt) {
      short8 vb0 = lds8(Vts + (dt * 16 + lrow) * 64 + lg * 8);
      short8 vb1 = lds8(Vts + (dt * 16 + lrow) * 64 + lg * 8 + 32);
      acco[dt] = __builtin_amdgcn_mfma_f32_16x16x32_bf16(pa0, vb0, acco[dt], 0, 0, 0);
      acco[dt] = __builtin_amdgcn_mfma_f32_16x16x32_bf16(pa1, vb1, acco[dt], 0, 0, 0);
    }
  }

  const int n = nh >> 4, h = nh & 15;
#pragma unroll
  for (int dt = 0; dt < 4; ++dt)
#pragma unroll
    for (int r = 0; r < 4; ++r) {
      const int lt = l0 + w * 16 + lg * 4 + r;
      const int col = h * 64 + dt * 16 + lrow;
      const float v = acco[dt][r] / zrow[r];
      oh[((size_t)lt * NB + n) * EE + col] = f2bf(v);
    }
  if (lrow == 0) {
#pragma unroll
    for (int r = 0; r < 4; ++r) {
      const int lt = l0 + w * 16 + lg * 4 + r;
      mbuf[(size_t)nh * LL + lt] = mrow[r];
      zbuf[(size_t)nh * LL + lt] = zrow[r];
    }
  }
}

// ---------- weights mean pass: out1[n][l][s] = (1/16) sum_h exp(s*scale - m)/Z ----------
__global__ __launch_bounds__(256) void weights_mean(const unsigned short* __restrict__ qh,
                                                    const unsigned short* __restrict__ kh,
                                                    const float* __restrict__ mbuf,
                                                    const float* __restrict__ zbuf,
                                                    float* __restrict__ out1) {
  __shared__ __align__(16) unsigned short Qs[64 * 64];
  __shared__ __align__(16) unsigned short Ks[64 * 64];
  const int tid = threadIdx.x, lane = tid & 63, w = tid >> 6;
  const int lrow = lane & 15, lg = lane >> 4;
  const int n = blockIdx.z;
  const int l0 = blockIdx.y * 64, s0 = blockIdx.x * 64;

  float accw[4][4] = {};
  for (int h = 0; h < HH; ++h) {
    const int nh = n * HH + h;
    __syncthreads();
    const unsigned short* qbase = qh + ((size_t)nh * LL + l0) * DD;
    const unsigned short* kbase = kh + ((size_t)nh * LL + s0) * DD;
    gload16(qbase + tid * 8,        (char*)Qs + tid * 16);
    gload16(qbase + tid * 8 + 2048, (char*)Qs + tid * 16 + 4096);
    gload16(kbase + tid * 8,        (char*)Ks + tid * 16);
    gload16(kbase + tid * 8 + 2048, (char*)Ks + tid * 16 + 4096);
    __syncthreads();

    short8 qa0 = lds8(Qs + (w * 16 + lrow) * 64 + lg * 8);
    short8 qa1 = lds8(Qs + (w * 16 + lrow) * 64 + lg * 8 + 32);
    f32x4 sc[4];
#pragma unroll
    for (int ct = 0; ct < 4; ++ct) {
      short8 b0 = lds8(Ks + (ct * 16 + lrow) * 64 + lg * 8);
      short8 b1 = lds8(Ks + (ct * 16 + lrow) * 64 + lg * 8 + 32);
      f32x4 a = {};
      a = __builtin_amdgcn_mfma_f32_16x16x32_bf16(qa0, b0, a, 0, 0, 0);
      a = __builtin_amdgcn_mfma_f32_16x16x32_bf16(qa1, b1, a, 0, 0, 0);
      sc[ct] = a;
    }
#pragma unroll
    for (int r = 0; r < 4; ++r) {
      const int lt = l0 + w * 16 + lg * 4 + r;
      const float m = mbuf[(size_t)nh * LL + lt];
      const float rz = 1.0f / zbuf[(size_t)nh * LL + lt];
#pragma unroll
      for (int ct = 0; ct < 4; ++ct)
        accw[ct][r] += __expf(sc[ct][r] * 0.125f - m) * rz;
    }
  }
#pragma unroll
  for (int ct = 0; ct < 4; ++ct)
#pragma unroll
    for (int r = 0; r < 4; ++r) {
      const int lt = l0 + w * 16 + lg * 4 + r;
      const int s = s0 + ct * 16 + lrow;
      out1[((size_t)n * LL + lt) * LL + s] = accw[ct][r] * 0.0625f;
    }
}

// ---------- launch ----------
extern "C" void kernel_launch(void* const* d_in, const int* in_sizes, int n_in,
                              void* d_out, int out_size, void* d_ws, size_t ws_size,
                              hipStream_t stream) {
  const float* query = (const float*)d_in[0];
  const float* key   = (const float*)d_in[1];
  const float* value = (const float*)d_in[2];
  const float* Wq = (const float*)d_in[3];
  const float* bq = (const float*)d_in[4];
  const float* Wk = (const float*)d_in[5];
  const float* bk = (const float*)d_in[6];
  const float* Wv = (const float*)d_in[7];
  const float* bv = (const float*)d_in[8];
  const float* Wo = (const float*)d_in[9];
  const float* bo = (const float*)d_in[10];

  float* out0 = (float*)d_out;                       // [2048,4,1024]
  float* out1 = out0 + (size_t)LL * NB * EE;         // [4,2048,2048]

  char* ws = (char*)d_ws;
  // ws layout (bytes)
  unsigned short* xbuf = (unsigned short*)(ws + 0);          // 16 MB, reused; also oh
  unsigned short* wqb  = (unsigned short*)(ws + 16777216);   // 2 MB each
  unsigned short* wkb  = (unsigned short*)(ws + 18874368);
  unsigned short* wvb  = (unsigned short*)(ws + 20971520);
  unsigned short* wob  = (unsigned short*)(ws + 23068672);
  unsigned short* qhb  = (unsigned short*)(ws + 25165824);   // 16 MB
  unsigned short* khb  = (unsigned short*)(ws + 41943040);   // 16 MB
  unsigned short* vthb = (unsigned short*)(ws + 58720256);   // 16 MB
  float* mbuf = (float*)(ws + 75497472);                     // 512 KB
  float* zbuf = (float*)(ws + 76021760);                     // 512 KB

  const int nTok = MROWS * EE;    // 8,388,608
  const int nW   = EE * EE;       // 1,048,576

  // weight conversions
  conv_bf16<<<nW / 1024, 256, 0, stream>>>(Wq, wqb);
  conv_bf16<<<nW / 1024, 256, 0, stream>>>(Wk, wkb);
  conv_bf16<<<nW / 1024, 256, 0, stream>>>(Wv, wvb);
  conv_bf16<<<nW / 1024, 256, 0, stream>>>(Wo, wob);

  dim3 ggrid(EE / 128, MROWS / 128);  // (8, 64)

  // Q projection
  conv_bf16<<<nTok / 1024, 256, 0, stream>>>(query, xbuf);
  gemm_bt<0><<<ggrid, 256, 0, stream>>>(xbuf, wqb, bq, qhb, nullptr);
  // K projection
  conv_bf16<<<nTok / 1024, 256, 0, stream>>>(key, xbuf);
  gemm_bt<0><<<ggrid, 256, 0, stream>>>(xbuf, wkb, bk, khb, nullptr);
  // V projection (transposed layout)
  conv_bf16<<<nTok / 1024, 256, 0, stream>>>(value, xbuf);
  gemm_bt<1><<<ggrid, 256, 0, stream>>>(xbuf, wvb, bv, vthb, nullptr);

  // flash attention -> oh (= xbuf), m/z
  flash_attn<<<dim3(LL / 64, NB * HH), 256, 0, stream>>>(qhb, khb, vthb, xbuf, mbuf, zbuf);

  // output projection -> out0
  gemm_bt<2><<<ggrid, 256, 0, stream>>>(xbuf, wob, bo, nullptr, out0);

  // head-mean attention weights -> out1
  weights_mean<<<dim3(LL / 64, LL / 64, NB), 256, 0, stream>>>(qhb, khb, mbuf, zbuf, out1);
}

// Round 2
// 511.310 us; speedup vs baseline: 1.0759x; 1.0759x over previous
//
#include <hip/hip_runtime.h>
#include <hip/hip_bf16.h>

// ---------- types & helpers ----------
typedef __attribute__((ext_vector_type(8))) short short8;   // 8 bf16 (4 VGPRs)
typedef __attribute__((ext_vector_type(4))) float f32x4;

#define AS1 __attribute__((address_space(1)))
#define AS3 __attribute__((address_space(3)))

__device__ __forceinline__ void gload16(const void* g, void* l) {
  __builtin_amdgcn_global_load_lds((const AS1 unsigned int*)g,
                                   (AS3 unsigned int*)l, 16, 0, 0);
}

__device__ __forceinline__ unsigned short f2bf(float x) {
  unsigned u = __float_as_uint(x);
  u = (u + 0x7FFFu + ((u >> 16) & 1u)) >> 16;  // RNE
  return (unsigned short)u;
}

__device__ __forceinline__ short8 lds8(const unsigned short* p) {
  return *(const short8*)p;
}

// Swizzled 16B LDS read: logical (row, byteInRow) of a 128B-row tile.
// Swizzle: byte ^= (row&7)<<4  (XOR on the 16B-slot index within the row).
__device__ __forceinline__ short8 lds8s(const unsigned short* base, int row, int byteInRow) {
  const int a = (row << 7) + (byteInRow ^ ((row & 7) << 4));
  return *(const short8*)((const char*)base + a);
}

// Problem constants: L=S=2048, N=4, E=1024, H=16, D=64; rows = L*N = 8192
#define LL 2048
#define NB 4
#define EE 1024
#define HH 16
#define DD 64
#define MROWS 8192
#define SC2 0.18033688f  // 0.125 * log2(e): softmax in exp2 domain

// ---------- fp32 -> bf16 convert ----------
__global__ __launch_bounds__(256) void conv_bf16(const float* __restrict__ src,
                                                 unsigned short* __restrict__ dst) {
  int i = blockIdx.x * 256 + threadIdx.x;
  float4 v = ((const float4*)src)[i];
  ushort4 o;
  o.x = f2bf(v.x); o.y = f2bf(v.y); o.z = f2bf(v.z); o.w = f2bf(v.w);
  ((ushort4*)dst)[i] = o;
}

// ---------- GEMM: C[8192,1024] = A[8192,1024] * B[1024,1024]^T + bias ----------
// MODE 0: bf16 head layout [n,h,l,d]; MODE 1: bf16 transposed [n,h,d,s]; MODE 2: fp32 rows
template <int MODE>
__global__ __launch_bounds__(256) void gemm_bt(const unsigned short* __restrict__ A,
                                               const unsigned short* __restrict__ B,
                                               const float* __restrict__ bias,
                                               unsigned short* __restrict__ outb,
                                               float* __restrict__ outf) {
  constexpr int K = 1024;
  __shared__ __align__(16) unsigned short As[128 * 32];
  __shared__ __align__(16) unsigned short Bs[128 * 32];
  const int tid = threadIdx.x;
  const int lane = tid & 63, w = tid >> 6;
  const int wr = w >> 1, wc = w & 1;           // 2x2 waves, each 64x64
  const int lrow = lane & 15, lg = lane >> 4;
  const int m0 = blockIdx.y * 128, n0 = blockIdx.x * 128;

  f32x4 acc[4][4] = {};

  const int srow = tid >> 2, sseg = tid & 3;   // staging map: 64 rows x 4 16B-segs
  for (int k0 = 0; k0 < K; k0 += 32) {
    __syncthreads();
    const unsigned short* ga = A + (size_t)(m0 + srow) * K + k0 + sseg * 8;
    gload16(ga,            (char*)As + tid * 16);
    gload16(ga + 64 * K,   (char*)As + tid * 16 + 4096);
    const unsigned short* gb = B + (size_t)(n0 + srow) * K + k0 + sseg * 8;
    gload16(gb,            (char*)Bs + tid * 16);
    gload16(gb + 64 * K,   (char*)Bs + tid * 16 + 4096);
    __syncthreads();

    short8 af[4], bf[4];
#pragma unroll
    for (int mt = 0; mt < 4; ++mt)
      af[mt] = lds8(As + (wr * 64 + mt * 16 + lrow) * 32 + lg * 8);
#pragma unroll
    for (int nt = 0; nt < 4; ++nt)
      bf[nt] = lds8(Bs + (wc * 64 + nt * 16 + lrow) * 32 + lg * 8);
#pragma unroll
    for (int mt = 0; mt < 4; ++mt)
#pragma unroll
      for (int nt = 0; nt < 4; ++nt)
        acc[mt][nt] = __builtin_amdgcn_mfma_f32_16x16x32_bf16(af[mt], bf[nt],
                                                              acc[mt][nt], 0, 0, 0);
  }

#pragma unroll
  for (int mt = 0; mt < 4; ++mt) {
#pragma unroll
    for (int nt = 0; nt < 4; ++nt) {
      const int col = n0 + wc * 64 + nt * 16 + lrow;
      const float bv = bias[col];
#pragma unroll
      for (int r = 0; r < 4; ++r) {
        const int row = m0 + wr * 64 + mt * 16 + lg * 4 + r;  // token-row = l*4+n
        const float v = acc[mt][nt][r] + bv;
        if (MODE == 0) {
          const int l = row >> 2, n = row & 3, h = col >> 6, d = col & 63;
          outb[(((size_t)(n * HH + h)) * LL + l) * DD + d] = f2bf(v);
        } else if (MODE == 1) {
          const int s = row >> 2, n = row & 3, h = col >> 6, d = col & 63;
          outb[(((size_t)(n * HH + h)) * DD + d) * LL + s] = f2bf(v);
        } else {
          outf[(size_t)row * EE + col] = v;
        }
      }
    }
  }
}

// ---------- flash attention per (n,h): 64 q-rows per block ----------
// Swizzled LDS (pre-swizzled global src, linear gload_lds dest, swizzled reads),
// double-buffered K/V (1 barrier/tile), exp2-domain softmax, defer-max, setprio.
__global__ __launch_bounds__(256) void flash_attn(const unsigned short* __restrict__ qh,
                                                  const unsigned short* __restrict__ kh,
                                                  const unsigned short* __restrict__ vth,
                                                  unsigned short* __restrict__ oh,
                                                  float* __restrict__ mbuf,
                                                  float* __restrict__ zbuf) {
  __shared__ __align__(16) unsigned short Ks[2][64 * 64];
  __shared__ __align__(16) unsigned short Vts[2][64 * 64];
  __shared__ __align__(16) unsigned short QPs[64 * 64];  // Q tile, then reused as P tile
  const int tid = threadIdx.x, lane = tid & 63, w = tid >> 6;
  const int lrow = lane & 15, lg = lane >> 4;
  const int nh = blockIdx.y;
  const int l0 = blockIdx.x * 64;

  const unsigned short* qbase = qh + ((size_t)nh * LL + l0) * DD;
  const unsigned short* kbase = kh + (size_t)nh * LL * DD;
  const unsigned short* vbase = vth + (size_t)nh * DD * LL;

  const int sr = tid >> 3;                      // staging row 0..31 (and +32)
  const int cs = ((tid & 7) ^ (sr & 7)) * 8;    // pre-swizzled col (shorts)

  // stage Q + tile 0 of K/V
  gload16(qbase + (size_t)sr * DD + cs,        (char*)QPs + tid * 16);
  gload16(qbase + (size_t)(sr + 32) * DD + cs, (char*)QPs + tid * 16 + 4096);
  gload16(kbase + (size_t)sr * DD + cs,        (char*)Ks[0] + tid * 16);
  gload16(kbase + (size_t)(sr + 32) * DD + cs, (char*)Ks[0] + tid * 16 + 4096);
  gload16(vbase + (size_t)sr * LL + cs,        (char*)Vts[0] + tid * 16);
  gload16(vbase + (size_t)(sr + 32) * LL + cs, (char*)Vts[0] + tid * 16 + 4096);
  __syncthreads();

  // Q fragments -> registers; QPs LDS rows (wave-private w*16..w*16+15) now free for P
  short8 qa0 = lds8s(QPs, w * 16 + lrow, lg * 16);
  short8 qa1 = lds8s(QPs, w * 16 + lrow, 64 + lg * 16);

  float mrow[4], zrow[4];
  f32x4 acco[4] = {};
#pragma unroll
  for (int r = 0; r < 4; ++r) { mrow[r] = -1e30f; zrow[r] = 0.f; }

  int cur = 0;
  for (int s0 = 0; s0 < LL; s0 += 64) {
    // prefetch next K/V tile into the other buffer (overlaps with compute below)
    if (s0 + 64 < LL) {
      const int nxt = cur ^ 1;
      const unsigned short* kt = kbase + (size_t)(s0 + 64) * DD;
      gload16(kt + (size_t)sr * DD + cs,        (char*)Ks[nxt] + tid * 16);
      gload16(kt + (size_t)(sr + 32) * DD + cs, (char*)Ks[nxt] + tid * 16 + 4096);
      gload16(vbase + (size_t)sr * LL + (s0 + 64) + cs,        (char*)Vts[nxt] + tid * 16);
      gload16(vbase + (size_t)(sr + 32) * LL + (s0 + 64) + cs, (char*)Vts[nxt] + tid * 16 + 4096);
    }

    // QK^T
    f32x4 sc[4];
    __builtin_amdgcn_s_setprio(1);
#pragma unroll
    for (int ct = 0; ct < 4; ++ct) {
      short8 b0 = lds8s(Ks[cur], ct * 16 + lrow, lg * 16);
      short8 b1 = lds8s(Ks[cur], ct * 16 + lrow, 64 + lg * 16);
      f32x4 a = {};
      a = __builtin_amdgcn_mfma_f32_16x16x32_bf16(qa0, b0, a, 0, 0, 0);
      a = __builtin_amdgcn_mfma_f32_16x16x32_bf16(qa1, b1, a, 0, 0, 0);
      sc[ct] = a;
    }
    __builtin_amdgcn_s_setprio(0);

    // row max in exp2 domain + deferred rescale (skip unless max grows > 2^8)
    float tmx[4];
    int need = 0;
#pragma unroll
    for (int r = 0; r < 4; ++r) {
      float t = fmaxf(fmaxf(sc[0][r], sc[1][r]), fmaxf(sc[2][r], sc[3][r]));
      t = fmaxf(t, __shfl_xor(t, 1));
      t = fmaxf(t, __shfl_xor(t, 2));
      t = fmaxf(t, __shfl_xor(t, 4));
      t = fmaxf(t, __shfl_xor(t, 8));
      tmx[r] = t * SC2;
      need |= (tmx[r] > mrow[r] + 8.0f) ? 1 : 0;
    }
    if (__any(need)) {
#pragma unroll
      for (int r = 0; r < 4; ++r) {
        const float mnew = fmaxf(mrow[r], tmx[r]);
        const float f = __builtin_exp2f(mrow[r] - mnew);
        mrow[r] = mnew;
        zrow[r] *= f;
#pragma unroll
        for (int dt = 0; dt < 4; ++dt) acco[dt][r] *= f;
      }
    }

    // P = exp2(sc*SC2 - m); sum into z; bf16 into wave-private P rows (swizzled)
#pragma unroll
    for (int r = 0; r < 4; ++r) {
      float ps = 0.f;
      const int row = w * 16 + lg * 4 + r;
#pragma unroll
      for (int ct = 0; ct < 4; ++ct) {
        const float e = __builtin_exp2f(sc[ct][r] * SC2 - mrow[r]);
        ps += e;
        const int a = (row << 7) + ((((ct * 16 + lrow) * 2)) ^ ((row & 7) << 4));
        *(__hip_bfloat16*)((char*)QPs + a) = __float2bfloat16(e);
      }
      ps += __shfl_xor(ps, 1);
      ps += __shfl_xor(ps, 2);
      ps += __shfl_xor(ps, 4);
      ps += __shfl_xor(ps, 8);
      zrow[r] += ps;
    }

    // PV (P rows are wave-private: no barrier needed between write and read)
    short8 pa0 = lds8s(QPs, w * 16 + lrow, lg * 16);
    short8 pa1 = lds8s(QPs, w * 16 + lrow, 64 + lg * 16);
    __builtin_amdgcn_s_setprio(1);
#pragma unroll
    for (int dt = 0; dt < 4; ++dt) {
      short8 vb0 = lds8s(Vts[cur], dt * 16 + lrow, lg * 16);
      short8 vb1 = lds8s(Vts[cur], dt * 16 + lrow, 64 + lg * 16);
      acco[dt] = __builtin_amdgcn_mfma_f32_16x16x32_bf16(pa0, vb0, acco[dt], 0, 0, 0);
      acco[dt] = __builtin_amdgcn_mfma_f32_16x16x32_bf16(pa1, vb1, acco[dt], 0, 0, 0);
    }
    __builtin_amdgcn_s_setprio(0);
    __syncthreads();   // staging done (vmcnt drained) + all reads of buf[cur] done
    cur ^= 1;
  }

  const int n = nh >> 4, h = nh & 15;
#pragma unroll
  for (int dt = 0; dt < 4; ++dt)
#pragma unroll
    for (int r = 0; r < 4; ++r) {
      const int lt = l0 + w * 16 + lg * 4 + r;
      const int col = h * 64 + dt * 16 + lrow;
      const float v = acco[dt][r] / zrow[r];
      oh[((size_t)lt * NB + n) * EE + col] = f2bf(v);
    }
  if (lrow == 0) {
#pragma unroll
    for (int r = 0; r < 4; ++r) {
      const int lt = l0 + w * 16 + lg * 4 + r;
      mbuf[(size_t)nh * LL + lt] = mrow[r];   // exp2-domain running max
      zbuf[(size_t)nh * LL + lt] = zrow[r];
    }
  }
}

// ---------- weights mean: out1[n][l][s] = (1/16) sum_h exp2(sc*SC2 - m)/Z ----------
__global__ __launch_bounds__(256) void weights_mean(const unsigned short* __restrict__ qh,
                                                    const unsigned short* __restrict__ kh,
                                                    const float* __restrict__ mbuf,
                                                    const float* __restrict__ zbuf,
                                                    float* __restrict__ out1) {
  __shared__ __align__(16) unsigned short Qs[64 * 64];
  __shared__ __align__(16) unsigned short Ks[64 * 64];
  const int tid = threadIdx.x, lane = tid & 63, w = tid >> 6;
  const int lrow = lane & 15, lg = lane >> 4;
  const int n = blockIdx.z;
  const int l0 = blockIdx.y * 64, s0 = blockIdx.x * 64;

  const int sr = tid >> 3;
  const int cs = ((tid & 7) ^ (sr & 7)) * 8;

  float accw[4][4] = {};
  for (int h = 0; h < HH; ++h) {
    const int nh = n * HH + h;
    __syncthreads();
    const unsigned short* qbase = qh + ((size_t)nh * LL + l0) * DD;
    const unsigned short* kbase = kh + ((size_t)nh * LL + s0) * DD;
    gload16(qbase + (size_t)sr * DD + cs,        (char*)Qs + tid * 16);
    gload16(qbase + (size_t)(sr + 32) * DD + cs, (char*)Qs + tid * 16 + 4096);
    gload16(kbase + (size_t)sr * DD + cs,        (char*)Ks + tid * 16);
    gload16(kbase + (size_t)(sr + 32) * DD + cs, (char*)Ks + tid * 16 + 4096);
    __syncthreads();

    short8 qa0 = lds8s(Qs, w * 16 + lrow, lg * 16);
    short8 qa1 = lds8s(Qs, w * 16 + lrow, 64 + lg * 16);
    f32x4 sc[4];
    __builtin_amdgcn_s_setprio(1);
#pragma unroll
    for (int ct = 0; ct < 4; ++ct) {
      short8 b0 = lds8s(Ks, ct * 16 + lrow, lg * 16);
      short8 b1 = lds8s(Ks, ct * 16 + lrow, 64 + lg * 16);
      f32x4 a = {};
      a = __builtin_amdgcn_mfma_f32_16x16x32_bf16(qa0, b0, a, 0, 0, 0);
      a = __builtin_amdgcn_mfma_f32_16x16x32_bf16(qa1, b1, a, 0, 0, 0);
      sc[ct] = a;
    }
    __builtin_amdgcn_s_setprio(0);
#pragma unroll
    for (int r = 0; r < 4; ++r) {
      const int lt = l0 + w * 16 + lg * 4 + r;
      const float m = mbuf[(size_t)nh * LL + lt];
      const float rz = 1.0f / zbuf[(size_t)nh * LL + lt];
#pragma unroll
      for (int ct = 0; ct < 4; ++ct)
        accw[ct][r] += __builtin_exp2f(sc[ct][r] * SC2 - m) * rz;
    }
  }
#pragma unroll
  for (int ct = 0; ct < 4; ++ct)
#pragma unroll
    for (int r = 0; r < 4; ++r) {
      const int lt = l0 + w * 16 + lg * 4 + r;
      const int s = s0 + ct * 16 + lrow;
      out1[((size_t)n * LL + lt) * LL + s] = accw[ct][r] * 0.0625f;
    }
}

// ---------- launch ----------
extern "C" void kernel_launch(void* const* d_in, const int* in_sizes, int n_in,
                              void* d_out, int out_size, void* d_ws, size_t ws_size,
                              hipStream_t stream) {
  const float* query = (const float*)d_in[0];
  const float* key   = (const float*)d_in[1];
  const float* value = (const float*)d_in[2];
  const float* Wq = (const float*)d_in[3];
  const float* bq = (const float*)d_in[4];
  const float* Wk = (const float*)d_in[5];
  const float* bk = (const float*)d_in[6];
  const float* Wv = (const float*)d_in[7];
  const float* bv = (const float*)d_in[8];
  const float* Wo = (const float*)d_in[9];
  const float* bo = (const float*)d_in[10];

  float* out0 = (float*)d_out;                       // [2048,4,1024]
  float* out1 = out0 + (size_t)LL * NB * EE;         // [4,2048,2048]

  char* ws = (char*)d_ws;
  unsigned short* xbuf = (unsigned short*)(ws + 0);          // 16 MB, reused; also oh
  unsigned short* wqb  = (unsigned short*)(ws + 16777216);   // 2 MB each
  unsigned short* wkb  = (unsigned short*)(ws + 18874368);
  unsigned short* wvb  = (unsigned short*)(ws + 20971520);
  unsigned short* wob  = (unsigned short*)(ws + 23068672);
  unsigned short* qhb  = (unsigned short*)(ws + 25165824);   // 16 MB
  unsigned short* khb  = (unsigned short*)(ws + 41943040);   // 16 MB
  unsigned short* vthb = (unsigned short*)(ws + 58720256);   // 16 MB
  float* mbuf = (float*)(ws + 75497472);                     // 512 KB
  float* zbuf = (float*)(ws + 76021760);                     // 512 KB

  const int nTok = MROWS * EE;    // 8,388,608
  const int nW   = EE * EE;       // 1,048,576

  conv_bf16<<<nW / 1024, 256, 0, stream>>>(Wq, wqb);
  conv_bf16<<<nW / 1024, 256, 0, stream>>>(Wk, wkb);
  conv_bf16<<<nW / 1024, 256, 0, stream>>>(Wv, wvb);
  conv_bf16<<<nW / 1024, 256, 0, stream>>>(Wo, wob);

  dim3 ggrid(EE / 128, MROWS / 128);  // (8, 64)

  conv_bf16<<<nTok / 1024, 256, 0, stream>>>(query, xbuf);
  gemm_bt<0><<<ggrid, 256, 0, stream>>>(xbuf, wqb, bq, qhb, nullptr);
  conv_bf16<<<nTok / 1024, 256, 0, stream>>>(key, xbuf);
  gemm_bt<0><<<ggrid, 256, 0, stream>>>(xbuf, wkb, bk, khb, nullptr);
  conv_bf16<<<nTok / 1024, 256, 0, stream>>>(value, xbuf);
  gemm_bt<1><<<ggrid, 256, 0, stream>>>(xbuf, wvb, bv, vthb, nullptr);

  flash_attn<<<dim3(LL / 64, NB * HH), 256, 0, stream>>>(qhb, khb, vthb, xbuf, mbuf, zbuf);

  gemm_bt<2><<<ggrid, 256, 0, stream>>>(xbuf, wob, bo, nullptr, out0);

  weights_mean<<<dim3(LL / 64, LL / 64, NB), 256, 0, stream>>>(qhb, khb, mbuf, zbuf, out1);
}